// Round 4
// baseline (211.111 us; speedup 1.0000x reference)
//
#include <hip/hip_runtime.h>

// ContactLoss R10: ONE kernel node (+ 8B memset node for counters).
//  - VB blocks: raycast (4 pts/thread, wave-uniform quad/triple/dual/single
//    loops — R9-validated __any selection; invdet-folded valid) | argmin.
//    Each VB block ends: __syncthreads + ONE release-scoped atomicAdd(done0).
//  - 32 reduce blocks (appended LAST in grid): spin on done0==nVB with
//    agent-scope acquire load + s_sleep, then run the R8 reduce tree VERBATIM
//    (128 (b,wv) wave units, bit-exact decomposition), done1-counter finalize
//    (R8 partials pattern), wave-local ordered-shfl final combine.
//  Deadlock-free: 32 spinners << resident capacity; spinners dispatch last.

#define RX 0.4395064455f
#define RY 0.617598629942f
#define RZ 0.652231566745f

#define MAXCHUNK_F4 512   // LDS float4 slots; >= max(chunkA,chunkB)*4
#define PTS_PER_BLK 1024  // 4 points per thread

struct Params {
    const float* hand_verts; const int* hand_faces;
    const float* obj_verts;  const int* obj_faces;
    const int* ovsplit; const int* ofsplit;
    int* hitsA;                // [CA*B*No] pass-A per-chunk hit counts
    int* hitsB;                // [CB*B*Nh] pass-B per-chunk hit counts
    float* anchor_h; float* anchor_o;
    float* partials;           // [B*16*6] per-(batch, virtual-wave) partials
    unsigned int* done;        // [0]=VB blocks done, [1]=reduce units done
    float* out;
    int B, Nh, Fh, No, Fo;
    int pbA, CA, chunkA, blocksA;
    int pbB, CB, chunkB, blocksB;
    int nMinBlk, nVB;
};

// ---------------------------------------------------------------------------
// Per-triangle precompute (absmax-0.0 lineage; valid folded into invdet=0,
// R7/R9-validated bit-exact).
// ---------------------------------------------------------------------------
__device__ __forceinline__ void tri_pre_one(const float* __restrict__ vb,
                                            const int* __restrict__ f,
                                            float4* o) {
#pragma clang fp contract(off)
    int i0 = f[0], i1 = f[1], i2 = f[2];
    float v0x = vb[i0*3+0], v0y = vb[i0*3+1], v0z = vb[i0*3+2];
    float v1x = vb[i1*3+0], v1y = vb[i1*3+1], v1z = vb[i1*3+2];
    float v2x = vb[i2*3+0], v2y = vb[i2*3+1], v2z = vb[i2*3+2];
    float e1x = v1x - v0x, e1y = v1y - v0y, e1z = v1z - v0z;
    float e2x = v2x - v0x, e2y = v2y - v0y, e2z = v2z - v0z;
    float px = RY*e2z - RZ*e2y;
    float py = RZ*e2x - RX*e2z;
    float pz = RX*e2y - RY*e2x;
    float det = (e1x*px + e1y*py) + e1z*pz;       // ((a+b)+c) like np.sum
    float invdet = 1.0f / (det + 1e-8f);          // 0.1*TOL, IEEE div
    if (fabsf(det) < 1e-7f) invdet = 0.0f;        // parallel => no hit, exactly
    o[0] = make_float4(v0x, v0y, v0z, invdet);
    o[1] = make_float4(e1x, e1y, e1z, 0.0f);
    o[2] = make_float4(e2x, e2y, e2z, 0.0f);
    o[3] = make_float4(px,  py,  pz,  0.0f);
}

// One Möller–Trumbore test (expression tree identical to absmax-0.0 lineage).
__device__ __forceinline__ int mt_test(float qx, float qy, float qz,
                                       const float4& f0, const float4& f1,
                                       const float4& f2, const float4& f3) {
#pragma clang fp contract(off)
    float tvx = qx - f0.x, tvy = qy - f0.y, tvz = qz - f0.z;
    float u  = ((tvx*f3.x + tvy*f3.y) + tvz*f3.z) * f0.w;
    float qvx = tvy*f1.z - tvz*f1.y;
    float qvy = tvz*f1.x - tvx*f1.z;
    float qvz = tvx*f1.y - tvy*f1.x;
    float v  = ((qvx*RX + qvy*RY) + qvz*RZ) * f0.w;
    float tt = ((f2.x*qvx + f2.y*qvy) + f2.z*qvz) * f0.w;
    bool hit = (u > 0.0f) && (u < 1.0f) && (v > 0.0f) &&
               ((u + v) < 1.0f) && (tt > 1e-7f);
    return hit ? 1 : 0;
}

// ---------------------------------------------------------------------------
// One raycast virtual block: chunk staged in LDS; each thread tests FOUR
// points. Loop depth chosen wave-uniformly by __any over monotone act masks
// (R9-validated selection; discarded lanes compute exactly as before).
// ---------------------------------------------------------------------------
__device__ __forceinline__ void raycast_vb(const Params& p, int vbid, int tid,
                                           float4* s_tri) {
#pragma clang fp contract(off)
    const float* pts; const float* tverts; const int* tfaces; int* slots;
    int P, T, Nv, c, pb, b, chunk, tlim, plim;
    if (vbid < p.blocksA) {
        int per_b = p.pbA * p.CA;
        b  = vbid / per_b;
        int r = vbid - b * per_b;
        c  = r / p.pbA;
        pb = r - c * p.pbA;
        pts = p.obj_verts; tverts = p.hand_verts; tfaces = p.hand_faces;
        slots = p.hitsA;
        P = p.No; T = p.Fh; Nv = p.Nh; chunk = p.chunkA;
        tlim = p.Fh; plim = min(p.No, p.ovsplit[b]);   // invalid pts never read
    } else {
        int j = vbid - p.blocksA;
        int per_b = p.pbB * p.CB;
        b  = j / per_b;
        int r = j - b * per_b;
        c  = r / p.pbB;
        pb = r - c * p.pbB;
        pts = p.hand_verts; tverts = p.obj_verts; tfaces = p.obj_faces;
        slots = p.hitsB;
        P = p.Nh; T = p.Fo; Nv = p.No; chunk = p.chunkB;
        tlim = min(p.Fo, p.ofsplit[b]); plim = p.Nh;
    }

    int tStart = c * chunk;
    if (tStart >= tlim) return;               // block-uniform (slots unread)
    if (pb * PTS_PER_BLK >= plim) return;     // block-uniform (slots unread)
    int nTri = min(tStart + chunk, tlim) - tStart;

    if (tid < nTri) {
        int t = tStart + tid;
        tri_pre_one(tverts + (size_t)b * Nv * 3,
                    tfaces + ((size_t)b * T + t) * 3,
                    s_tri + (size_t)tid * 4);
    }

    int p1 = pb * PTS_PER_BLK + tid;
    int p2 = p1 + 256, p3 = p1 + 512, p4 = p1 + 768;
    bool act1 = p1 < plim, act2 = p2 < plim, act3 = p3 < plim, act4 = p4 < plim;
    float q1x=0.f,q1y=0.f,q1z=0.f, q2x=0.f,q2y=0.f,q2z=0.f;
    float q3x=0.f,q3y=0.f,q3z=0.f, q4x=0.f,q4y=0.f,q4z=0.f;
    if (act1) { const float* q = pts + ((size_t)b*P + p1)*3; q1x=q[0]; q1y=q[1]; q1z=q[2]; }
    if (act2) { const float* q = pts + ((size_t)b*P + p2)*3; q2x=q[0]; q2y=q[1]; q2z=q[2]; }
    if (act3) { const float* q = pts + ((size_t)b*P + p3)*3; q3x=q[0]; q3y=q[1]; q3z=q[2]; }
    if (act4) { const float* q = pts + ((size_t)b*P + p4)*3; q4x=q[0]; q4y=q[1]; q4z=q[2]; }
    __syncthreads();

    if (!act1) return;                        // act masks are monotone
    int c1=0, c2=0, c3=0, c4=0;
    if (__any(act4)) {
        for (int i = 0; i < nTri; ++i) {
            const float4 f0 = s_tri[(i<<2)+0];
            const float4 f1 = s_tri[(i<<2)+1];
            const float4 f2 = s_tri[(i<<2)+2];
            const float4 f3 = s_tri[(i<<2)+3];
            c1 += mt_test(q1x,q1y,q1z, f0,f1,f2,f3);
            c2 += mt_test(q2x,q2y,q2z, f0,f1,f2,f3);
            c3 += mt_test(q3x,q3y,q3z, f0,f1,f2,f3);
            c4 += mt_test(q4x,q4y,q4z, f0,f1,f2,f3);
        }
    } else if (__any(act3)) {
        for (int i = 0; i < nTri; ++i) {
            const float4 f0 = s_tri[(i<<2)+0];
            const float4 f1 = s_tri[(i<<2)+1];
            const float4 f2 = s_tri[(i<<2)+2];
            const float4 f3 = s_tri[(i<<2)+3];
            c1 += mt_test(q1x,q1y,q1z, f0,f1,f2,f3);
            c2 += mt_test(q2x,q2y,q2z, f0,f1,f2,f3);
            c3 += mt_test(q3x,q3y,q3z, f0,f1,f2,f3);
        }
    } else if (__any(act2)) {
        for (int i = 0; i < nTri; ++i) {
            const float4 f0 = s_tri[(i<<2)+0];
            const float4 f1 = s_tri[(i<<2)+1];
            const float4 f2 = s_tri[(i<<2)+2];
            const float4 f3 = s_tri[(i<<2)+3];
            c1 += mt_test(q1x,q1y,q1z, f0,f1,f2,f3);
            c2 += mt_test(q2x,q2y,q2z, f0,f1,f2,f3);
        }
    } else {
        for (int i = 0; i < nTri; ++i) {
            const float4 f0 = s_tri[(i<<2)+0];
            const float4 f1 = s_tri[(i<<2)+1];
            const float4 f2 = s_tri[(i<<2)+2];
            const float4 f3 = s_tri[(i<<2)+3];
            c1 += mt_test(q1x,q1y,q1z, f0,f1,f2,f3);
        }
    }
    int* base = slots + ((size_t)(c * p.B + b)) * P;
    base[p1] = c1;                            // plain stores, no atomics
    if (act2) base[p2] = c2;
    if (act3) base[p3] = c3;
    if (act4) base[p4] = c4;
}

// ---------------------------------------------------------------------------
// One argmin wave. Packed (dist<<32)|idx min => np.argmin tie-break.
// ---------------------------------------------------------------------------
__device__ __forceinline__ void min_one(const Params& p, int w, int lane) {
#pragma clang fp contract(off)
    int nHand = p.B * p.Nh;
    const float* refv; const float* loopv; int loopN; float* outp;
    if (w < nHand) {
        int b = w / p.Nh;
        int n = w - b * p.Nh;
        refv  = p.hand_verts + ((size_t)b * p.Nh + n) * 3;
        loopv = p.obj_verts + (size_t)b * p.No * 3;
        loopN = p.ovsplit[b];
        outp  = p.anchor_h + (size_t)b * p.Nh + n;
    } else {
        int j = w - nHand;
        int b = j / p.No;
        int m = j - b * p.No;
        if (m >= p.ovsplit[b]) return;
        refv  = p.obj_verts + ((size_t)b * p.No + m) * 3;
        loopv = p.hand_verts + (size_t)b * p.Nh * 3;
        loopN = p.Nh;
        outp  = p.anchor_o + (size_t)b * p.No + m;
    }
    float hx = refv[0], hy = refv[1], hz = refv[2];
    float rx = (hx*hx + hy*hy) + hz*hz;
    unsigned long long best = ~0ull;
    for (int m = lane; m < loopN; m += 64) {
        float ox = loopv[m*3+0], oy = loopv[m*3+1], oz = loopv[m*3+2];
        float ry = (ox*ox + oy*oy) + oz*oz;
        float zz = (hx*ox + hy*oy) + hz*oz;
        float d = (rx + ry) - 2.0f * zz;
        unsigned long long e = ((unsigned long long)__float_as_uint(d) << 32) | (unsigned)m;
        if (e < best) best = e;
    }
    for (int off = 32; off > 0; off >>= 1) {
        unsigned long long o = __shfl_xor(best, off, 64);
        if (o < best) best = o;
    }
    if (lane == 0) {
        int idx = (best == ~0ull) ? 0 : (int)(best & 0xffffffffu);
        const float* cv = loopv + (size_t)idx * 3;
        float dx = cv[0] - hx, dy = cv[1] - hy, dz = cv[2] - hz;
        *outp = sqrtf((dx*dx + dy*dy) + dz*dz);
    }
}

// ---------------------------------------------------------------------------
// One reduce wave unit: (batch b = unit>>4, virtual wave wv = unit&15) of the
// old 1024-thread tree — R8 verbatim body. Finalize is wave-local with
// ordered __shfl (same w2-then-batch add order => bit-exact).
// ---------------------------------------------------------------------------
__device__ void reduce_unit(const Params& p, int unit, int lane) {
    const int b  = unit >> 4;
    const int wv = unit & 15;
    const int vt = wv * 64 + lane;            // virtual tid 0..1023
    float s0=0.f,s1=0.f,s2=0.f,s3=0.f,s4=0.f,s5=0.f;

    int tlimB = min(p.Fo, p.ofsplit[b]);
    int nCB = (tlimB + p.chunkB - 1) / p.chunkB;        // valid pass-B chunks
    for (int n = vt; n < p.Nh; n += 1024) {
        int par = 0;
        for (int c = 0; c < nCB; ++c)
            par += p.hitsB[((size_t)(c * p.B + b)) * p.Nh + n];
        bool ext = (par & 1) == 0;
        float val = 25.0f * tanhf(p.anchor_h[(size_t)b*p.Nh + n] / 25.0f);
        if (ext) { s0 += val; s1 += 1.0f; } else { s2 += val; s3 += 1.0f; }
    }
    int split = p.ovsplit[b];
    for (int m = vt; m < split; m += 1024) {
        int par = 0;
        for (int c = 0; c < p.CA; ++c)
            par += p.hitsA[((size_t)(c * p.B + b)) * p.No + m];
        if (par & 1) {                                   // interior & valid
            s4 += 25.0f * tanhf(p.anchor_o[(size_t)b*p.No + m] / 25.0f);
            s5 += 1.0f;
        }
    }
    for (int off = 32; off > 0; off >>= 1) {
        s0 += __shfl_xor(s0, off, 64);
        s1 += __shfl_xor(s1, off, 64);
        s2 += __shfl_xor(s2, off, 64);
        s3 += __shfl_xor(s3, off, 64);
        s4 += __shfl_xor(s4, off, 64);
        s5 += __shfl_xor(s5, off, 64);
    }

    unsigned int old = 0u;
    if (lane == 0) {
        float* q = p.partials + ((size_t)(b * 16 + wv)) * 6;
        q[0]=s0; q[1]=s1; q[2]=s2; q[3]=s3; q[4]=s4; q[5]=s5;
        __threadfence();                     // release partials (R8 pattern)
        old = atomicAdd(&p.done[1], 1u);
    }
    old = __shfl(old, 0);
    if (old != (unsigned int)(p.B * 16 - 1)) return;   // only last unit
    __threadfence();                         // acquire others' partials

    float t0=0.f,t1=0.f,t2=0.f,t3=0.f,t4=0.f,t5=0.f;
    if (lane < p.B) {
        int bb = lane;
        for (int w2 = 0; w2 < 16; ++w2) {     // same wave order as old loop
            const float* q = p.partials + ((size_t)(bb * 16 + w2)) * 6;
            t0 += q[0]; t1 += q[1]; t2 += q[2];
            t3 += q[3]; t4 += q[4]; t5 += q[5];
        }
        p.out[2 + bb]  = (t1 > 0.f) ? t0 / fmaxf(t1, 1.f) : 0.f;
        float ph       = (t3 > 0.f) ? t2 / fmaxf(t3, 1.f) : 0.f;
        float po       = (t5 > 0.f) ? t4 / fmaxf(t5, 1.f) : 0.f;
        p.out[10 + bb] = ph + po;
    }
    float sm=0.f,cm=0.f,sph=0.f,cph=0.f,spo=0.f,cpo=0.f;
    for (int bb = 0; bb < p.B; ++bb) {        // same batch order as old final
        sm  += __shfl(t0, bb); cm  += __shfl(t1, bb); sph += __shfl(t2, bb);
        cph += __shfl(t3, bb); spo += __shfl(t4, bb); cpo += __shfl(t5, bb);
    }
    if (lane == 0) {
        float missed = (cm  > 0.f) ? sm  / fmaxf(cm , 1.f) : 0.f;
        float ph     = (cph > 0.f) ? sph / fmaxf(cph, 1.f) : 0.f;
        float po     = (cpo > 0.f) ? spo / fmaxf(cpo, 1.f) : 0.f;
        p.out[0] = missed;
        p.out[1] = ph + po;
    }
}

// ---------------------------------------------------------------------------
// mega: [raycast VBs | argmin blocks | 32 reduce blocks (spin-tail)].
// ---------------------------------------------------------------------------
__global__ __launch_bounds__(256) void mega(Params p) {
    __shared__ float4 s_tri[MAXCHUNK_F4];
    const int tid = threadIdx.x;
    const int bid = blockIdx.x;
    const int nRay = p.blocksA + p.blocksB;

    if (bid < p.nVB) {
        if (bid < nRay) {
            raycast_vb(p, bid, tid, s_tri);
        } else {
            int w = (bid - nRay) * 4 + (tid >> 6);
            if (w < p.B * (p.Nh + p.No)) min_one(p, w, tid & 63);
        }
        __syncthreads();                      // all waves' stores drained
        if (tid == 0)                         // release: flush + count
            __hip_atomic_fetch_add(&p.done[0], 1u, __ATOMIC_RELEASE,
                                   __HIP_MEMORY_SCOPE_AGENT);
    } else {
        int unit = (bid - p.nVB) * 4 + (tid >> 6);
        int lane = tid & 63;
        if (unit < p.B * 16) {
            if (lane == 0) {                  // wave-lockstep spin
                while (__hip_atomic_load(&p.done[0], __ATOMIC_ACQUIRE,
                                         __HIP_MEMORY_SCOPE_AGENT)
                       < (unsigned int)p.nVB)
                    __builtin_amdgcn_s_sleep(32);
            }
            __threadfence();                  // acquire hits/anchors
            reduce_unit(p, unit, lane);
        }
    }
}

// ---------------------------------------------------------------------------
extern "C" void kernel_launch(void* const* d_in, const int* in_sizes, int n_in,
                              void* d_out, int out_size, void* d_ws, size_t ws_size,
                              hipStream_t stream) {
    Params p;
    p.hand_verts = (const float*)d_in[0];
    p.hand_faces = (const int*)d_in[1];
    p.obj_verts  = (const float*)d_in[2];
    p.obj_faces  = (const int*)d_in[3];
    p.ovsplit    = (const int*)d_in[4];
    p.ofsplit    = (const int*)d_in[5];
    p.out        = (float*)d_out;

    p.B  = in_sizes[4];
    p.Nh = in_sizes[0] / (3 * p.B);
    p.Fh = in_sizes[1] / (3 * p.B);
    p.No = in_sizes[2] / (3 * p.B);
    p.Fo = in_sizes[3] / (3 * p.B);

    p.CA = 16; p.CB = 32;
    p.chunkA = (p.Fh + p.CA - 1) / p.CA;       // 97  for Fh=1538 (388 f4 <= 512)
    p.chunkB = (p.Fo + p.CB - 1) / p.CB;       // 125 for Fo=4000 (500 f4 <= 512)
    p.pbA = (p.No + PTS_PER_BLK - 1) / PTS_PER_BLK;   // 2
    p.pbB = (p.Nh + PTS_PER_BLK - 1) / PTS_PER_BLK;   // 1
    p.blocksA = p.pbA * p.CA * p.B;            // 256
    p.blocksB = p.pbB * p.CB * p.B;            // 256

    int totalMin = p.B * (p.Nh + p.No);
    p.nMinBlk = (totalMin + 3) / 4;            // 4 argmin waves per block
    p.nVB = p.blocksA + p.blocksB + p.nMinBlk;
    int nRed = (p.B * 16 + 3) / 4;             // 4 reduce waves per block
    int grid = p.nVB + nRed;

    char* ws = (char*)d_ws;
    size_t off = 0;
    auto alloc = [&](size_t bytes) -> void* {
        void* q = ws + off;
        off = (off + bytes + 255) & ~(size_t)255;
        return q;
    };
    p.hitsA    = (int*)   alloc((size_t)p.CA * p.B * p.No * sizeof(int));
    p.hitsB    = (int*)   alloc((size_t)p.CB * p.B * p.Nh * sizeof(int));
    p.anchor_h = (float*) alloc((size_t)p.B * p.Nh * sizeof(float));
    p.anchor_o = (float*) alloc((size_t)p.B * p.No * sizeof(float));
    p.partials = (float*) alloc((size_t)p.B * 16 * 6 * sizeof(float));
    p.done     = (unsigned int*)alloc(2 * sizeof(unsigned int));

    hipMemsetAsync((void*)p.done, 0, 2 * sizeof(unsigned int), stream);
    mega<<<grid, 256, 0, stream>>>(p);
}

// Round 6
// 177.214 us; speedup vs baseline: 1.1913x; 1.1913x over previous
//
#include <hip/hip_runtime.h>

// ContactLoss R12: R11 transposed-raycast, compile-fixed (no writelane
// builtin on this ROCm; pc is wave-uniform so lane-select cndmask is exact).
//  - mega: raycast TRANSPOSED — one tri per LANE (13 VGPRs, precomputed
//    inline), point broadcast via readlane (SGPR), 64 tests/iter, count =
//    popcount(ballot(hit)) deposited via (lane==j) select. NO LDS/sync.
//    Tri ranges of 64 (one wave-load) => hits slots [range][B][P].
//    argmin waves unchanged (R6 lineage).
//  - reduce_fin: R8/R9 verbatim except parity loops over the new range
//    counts (25 for pass A, ceil(tlim/64) for pass B). Done-counter +
//    fence finalize (boundary-ordered reset in mega block 0).

#define RX 0.4395064455f
#define RY 0.617598629942f
#define RZ 0.652231566745f

#define PTS_PER_TASK 128   // 2 broadcast points per lane-slot

struct Params {
    const float* hand_verts; const int* hand_faces;
    const float* obj_verts;  const int* obj_faces;
    const int* ovsplit; const int* ofsplit;
    int* hitsA;                // [nRangeA*B*No] pass-A per-range hit counts
    int* hitsB;                // [nRangeB*B*Nh] pass-B per-range hit counts
    float* anchor_h; float* anchor_o;
    float* partials;           // [B*16*6] per-(batch, virtual-wave) partials
    unsigned int* done;
    float* out;
    int B, Nh, Fh, No, Fo;
    int nRangeA, nPSA, taskA;  // ranges of 64 tris; point-sets of 128
    int nRangeB, nPSB, taskB;
    int nRayW;                 // taskA + taskB
};

// ---------------------------------------------------------------------------
// One raycast WAVE task: lane = one triangle of range r (precomputed into
// VGPRs, absmax-0.0 lineage arithmetic; invalid/parallel => invdet=0, which
// forces hit=false exactly — R7/R9-validated). 128 points broadcast one at a
// time via readlane; per point, 64 tests in one pass; count via
// popcount(ballot) + lane-select. Plain stores, no atomics, no LDS.
// ---------------------------------------------------------------------------
__device__ __forceinline__ void raycast_wave(const Params& p, int w, int lane) {
#pragma clang fp contract(off)
    const float* pts; const float* tverts; const int* tfaces; int* slots;
    int P, T, Nv, b, r, ps, tlim, plim;
    if (w < p.taskA) {
        int perB = p.nRangeA * p.nPSA;
        b = w / perB; int rem = w - b * perB;
        r = rem / p.nPSA; ps = rem - r * p.nPSA;
        pts = p.obj_verts; tverts = p.hand_verts; tfaces = p.hand_faces;
        slots = p.hitsA; P = p.No; T = p.Fh; Nv = p.Nh;
        tlim = p.Fh; plim = min(p.No, p.ovsplit[b]);   // invalid pts never used
    } else {
        int j = w - p.taskA;
        int perB = p.nRangeB * p.nPSB;
        b = j / perB; int rem = j - b * perB;
        r = rem / p.nPSB; ps = rem - r * p.nPSB;
        pts = p.hand_verts; tverts = p.obj_verts; tfaces = p.obj_faces;
        slots = p.hitsB; P = p.Nh; T = p.Fo; Nv = p.No;
        tlim = min(p.Fo, p.ofsplit[b]); plim = p.Nh;
    }

    int pBase = ps * PTS_PER_TASK;
    if (pBase >= plim) return;                // wave-uniform
    if (r * 64 >= tlim) return;               // wave-uniform (slots unread)

    // ---- my triangle (clamped load; forced miss if out of range) ----
    int t  = r * 64 + lane;
    int tc = min(t, tlim - 1);
    const int* f = tfaces + ((size_t)b * T + tc) * 3;
    const float* vb = tverts + (size_t)b * Nv * 3;
    int i0 = f[0], i1 = f[1], i2 = f[2];
    float v0x = vb[i0*3+0], v0y = vb[i0*3+1], v0z = vb[i0*3+2];
    float v1x = vb[i1*3+0], v1y = vb[i1*3+1], v1z = vb[i1*3+2];
    float v2x = vb[i2*3+0], v2y = vb[i2*3+1], v2z = vb[i2*3+2];
    float e1x = v1x - v0x, e1y = v1y - v0y, e1z = v1z - v0z;
    float e2x = v2x - v0x, e2y = v2y - v0y, e2z = v2z - v0z;
    float px = RY*e2z - RZ*e2y;
    float py = RZ*e2x - RX*e2z;
    float pz = RX*e2y - RY*e2x;
    float det = (e1x*px + e1y*py) + e1z*pz;       // ((a+b)+c) like np.sum
    float invdet = 1.0f / (det + 1e-8f);          // 0.1*TOL, IEEE div
    if (t >= tlim || fabsf(det) < 1e-7f) invdet = 0.0f;  // miss, exactly

    // ---- my two broadcast points (clamped loads; results discarded) ----
    int p0 = pBase + lane, p1 = p0 + 64;
    bool a0 = p0 < plim, a1 = p1 < plim;
    int pc0 = min(p0, plim - 1), pc1 = min(p1, plim - 1);
    const float* q0 = pts + ((size_t)b * P + pc0) * 3;
    const float* q1 = pts + ((size_t)b * P + pc1) * 3;
    float q0x = q0[0], q0y = q0[1], q0z = q0[2];
    float q1x = q1[0], q1y = q1[1], q1z = q1[2];

    int live0 = min(plim - pBase, 64);
    int live1 = min(max(plim - pBase - 64, 0), 64);
    int cnt0 = 0, cnt1 = 0;

    for (int j = 0; j < live0; ++j) {
        float qx = __int_as_float(__builtin_amdgcn_readlane(__float_as_int(q0x), j));
        float qy = __int_as_float(__builtin_amdgcn_readlane(__float_as_int(q0y), j));
        float qz = __int_as_float(__builtin_amdgcn_readlane(__float_as_int(q0z), j));
        float tvx = qx - v0x, tvy = qy - v0y, tvz = qz - v0z;
        float u  = ((tvx*px + tvy*py) + tvz*pz) * invdet;
        float qvx = tvy*e1z - tvz*e1y;
        float qvy = tvz*e1x - tvx*e1z;
        float qvz = tvx*e1y - tvy*e1x;
        float v  = ((qvx*RX + qvy*RY) + qvz*RZ) * invdet;
        float tt = ((e2x*qvx + e2y*qvy) + e2z*qvz) * invdet;
        bool hit = (u > 0.0f) && (u < 1.0f) && (v > 0.0f) &&
                   ((u + v) < 1.0f) && (tt > 1e-7f);
        int pc = __popcll(__ballot(hit));     // wave-uniform exact sum
        cnt0 = (lane == j) ? pc : cnt0;       // deposit into lane j
    }
    for (int j = 0; j < live1; ++j) {
        float qx = __int_as_float(__builtin_amdgcn_readlane(__float_as_int(q1x), j));
        float qy = __int_as_float(__builtin_amdgcn_readlane(__float_as_int(q1y), j));
        float qz = __int_as_float(__builtin_amdgcn_readlane(__float_as_int(q1z), j));
        float tvx = qx - v0x, tvy = qy - v0y, tvz = qz - v0z;
        float u  = ((tvx*px + tvy*py) + tvz*pz) * invdet;
        float qvx = tvy*e1z - tvz*e1y;
        float qvy = tvz*e1x - tvx*e1z;
        float qvz = tvx*e1y - tvy*e1x;
        float v  = ((qvx*RX + qvy*RY) + qvz*RZ) * invdet;
        float tt = ((e2x*qvx + e2y*qvy) + e2z*qvz) * invdet;
        bool hit = (u > 0.0f) && (u < 1.0f) && (v > 0.0f) &&
                   ((u + v) < 1.0f) && (tt > 1e-7f);
        int pc = __popcll(__ballot(hit));
        cnt1 = (lane == j) ? pc : cnt1;
    }

    int* base = slots + ((size_t)(r * p.B + b)) * P;
    if (a0) base[p0] = cnt0;
    if (a1) base[p1] = cnt1;
}

// ---------------------------------------------------------------------------
// One argmin wave. Packed (dist<<32)|idx min => np.argmin tie-break. Unchanged.
// ---------------------------------------------------------------------------
__device__ __forceinline__ void min_one(const Params& p, int w, int lane) {
#pragma clang fp contract(off)
    int nHand = p.B * p.Nh;
    const float* refv; const float* loopv; int loopN; float* outp;
    if (w < nHand) {
        int b = w / p.Nh;
        int n = w - b * p.Nh;
        refv  = p.hand_verts + ((size_t)b * p.Nh + n) * 3;
        loopv = p.obj_verts + (size_t)b * p.No * 3;
        loopN = p.ovsplit[b];
        outp  = p.anchor_h + (size_t)b * p.Nh + n;
    } else {
        int j = w - nHand;
        int b = j / p.No;
        int m = j - b * p.No;
        if (m >= p.ovsplit[b]) return;
        refv  = p.obj_verts + ((size_t)b * p.No + m) * 3;
        loopv = p.hand_verts + (size_t)b * p.Nh * 3;
        loopN = p.Nh;
        outp  = p.anchor_o + (size_t)b * p.No + m;
    }
    float hx = refv[0], hy = refv[1], hz = refv[2];
    float rx = (hx*hx + hy*hy) + hz*hz;
    unsigned long long best = ~0ull;
    for (int m = lane; m < loopN; m += 64) {
        float ox = loopv[m*3+0], oy = loopv[m*3+1], oz = loopv[m*3+2];
        float ry = (ox*ox + oy*oy) + oz*oz;
        float zz = (hx*ox + hy*oy) + hz*oz;
        float d = (rx + ry) - 2.0f * zz;
        unsigned long long e = ((unsigned long long)__float_as_uint(d) << 32) | (unsigned)m;
        if (e < best) best = e;
    }
    for (int off = 32; off > 0; off >>= 1) {
        unsigned long long o = __shfl_xor(best, off, 64);
        if (o < best) best = o;
    }
    if (lane == 0) {
        int idx = (best == ~0ull) ? 0 : (int)(best & 0xffffffffu);
        const float* cv = loopv + (size_t)idx * 3;
        float dx = cv[0] - hx, dy = cv[1] - hy, dz = cv[2] - hz;
        *outp = sqrtf((dx*dx + dy*dy) + dz*dz);
    }
}

// ---------------------------------------------------------------------------
// mega: unified wave tasks [raycast | argmin]; resets done counter.
// No __shared__ at all.
// ---------------------------------------------------------------------------
__global__ __launch_bounds__(256) void mega(Params p) {
    const int tid = threadIdx.x;
    const int bid = blockIdx.x;
    if (bid == 0 && tid == 0) *p.done = 0u;   // visible to reduce_fin at boundary
    int w = bid * 4 + (tid >> 6);
    int lane = tid & 63;
    if (w < p.nRayW) {
        raycast_wave(p, w, lane);
    } else {
        int mw = w - p.nRayW;
        if (mw < p.B * (p.Nh + p.No)) min_one(p, mw, lane);
    }
}

// ---------------------------------------------------------------------------
// reduce_fin: 128 single-wave blocks (R8/R9 pattern). Block r = (batch
// b=r>>4, virtual wave wv=r&15) of the old 1024-thread tree; bit-exact
// decomposition; done-counter + fence finalize. Parity loops over ranges.
// ---------------------------------------------------------------------------
__global__ __launch_bounds__(64) void reduce_fin(Params p) {
    const int r    = blockIdx.x;
    const int b    = r >> 4;
    const int wv   = r & 15;
    const int lane = threadIdx.x;
    const int vt   = wv * 64 + lane;          // virtual tid 0..1023
    float s0=0.f,s1=0.f,s2=0.f,s3=0.f,s4=0.f,s5=0.f;

    int tlimB = min(p.Fo, p.ofsplit[b]);
    int nCB = (tlimB + 63) >> 6;              // valid pass-B ranges
    for (int n = vt; n < p.Nh; n += 1024) {
        int par = 0;
        for (int c = 0; c < nCB; ++c)
            par += p.hitsB[((size_t)(c * p.B + b)) * p.Nh + n];
        bool ext = (par & 1) == 0;
        float val = 25.0f * tanhf(p.anchor_h[(size_t)b*p.Nh + n] / 25.0f);
        if (ext) { s0 += val; s1 += 1.0f; } else { s2 += val; s3 += 1.0f; }
    }
    int split = p.ovsplit[b];
    for (int m = vt; m < split; m += 1024) {
        int par = 0;
        for (int c = 0; c < p.nRangeA; ++c)
            par += p.hitsA[((size_t)(c * p.B + b)) * p.No + m];
        if (par & 1) {                                   // interior & valid
            s4 += 25.0f * tanhf(p.anchor_o[(size_t)b*p.No + m] / 25.0f);
            s5 += 1.0f;
        }
    }
    for (int off = 32; off > 0; off >>= 1) {
        s0 += __shfl_xor(s0, off, 64);
        s1 += __shfl_xor(s1, off, 64);
        s2 += __shfl_xor(s2, off, 64);
        s3 += __shfl_xor(s3, off, 64);
        s4 += __shfl_xor(s4, off, 64);
        s5 += __shfl_xor(s5, off, 64);
    }

    __shared__ bool s_last;
    if (lane == 0) {
        float* q = p.partials + ((size_t)(b * 16 + wv)) * 6;
        q[0]=s0; q[1]=s1; q[2]=s2; q[3]=s3; q[4]=s4; q[5]=s5;
        __threadfence();                     // release partials
        unsigned int old = atomicAdd(p.done, 1u);
        s_last = (old == (unsigned int)(gridDim.x - 1));
    }
    __syncthreads();
    if (!s_last) return;
    __threadfence();                         // acquire others' partials

    __shared__ float s_red[16][6];
    if (lane < p.B && lane < 16) {
        int bb = lane;
        float t0=0.f,t1=0.f,t2=0.f,t3=0.f,t4=0.f,t5=0.f;
        for (int w2 = 0; w2 < 16; ++w2) {     // same wave order as old loop
            const float* q = p.partials + ((size_t)(bb * 16 + w2)) * 6;
            t0 += q[0]; t1 += q[1]; t2 += q[2];
            t3 += q[3]; t4 += q[4]; t5 += q[5];
        }
        p.out[2 + bb]  = (t1 > 0.f) ? t0 / fmaxf(t1, 1.f) : 0.f;
        float ph       = (t3 > 0.f) ? t2 / fmaxf(t3, 1.f) : 0.f;
        float po       = (t5 > 0.f) ? t4 / fmaxf(t5, 1.f) : 0.f;
        p.out[10 + bb] = ph + po;
        s_red[bb][0]=t0; s_red[bb][1]=t1; s_red[bb][2]=t2;
        s_red[bb][3]=t3; s_red[bb][4]=t4; s_red[bb][5]=t5;
    }
    __syncthreads();
    if (lane == 0) {
        float sm=0.f,cm=0.f,sph=0.f,cph=0.f,spo=0.f,cpo=0.f;
        for (int bb = 0; bb < p.B; ++bb) {    // same batch order as old final
            sm  += s_red[bb][0]; cm  += s_red[bb][1]; sph += s_red[bb][2];
            cph += s_red[bb][3]; spo += s_red[bb][4]; cpo += s_red[bb][5];
        }
        float missed = (cm  > 0.f) ? sm  / fmaxf(cm , 1.f) : 0.f;
        float ph     = (cph > 0.f) ? sph / fmaxf(cph, 1.f) : 0.f;
        float po     = (cpo > 0.f) ? spo / fmaxf(cpo, 1.f) : 0.f;
        p.out[0] = missed;
        p.out[1] = ph + po;
    }
}

// ---------------------------------------------------------------------------
extern "C" void kernel_launch(void* const* d_in, const int* in_sizes, int n_in,
                              void* d_out, int out_size, void* d_ws, size_t ws_size,
                              hipStream_t stream) {
    Params p;
    p.hand_verts = (const float*)d_in[0];
    p.hand_faces = (const int*)d_in[1];
    p.obj_verts  = (const float*)d_in[2];
    p.obj_faces  = (const int*)d_in[3];
    p.ovsplit    = (const int*)d_in[4];
    p.ofsplit    = (const int*)d_in[5];
    p.out        = (float*)d_out;

    p.B  = in_sizes[4];
    p.Nh = in_sizes[0] / (3 * p.B);
    p.Fh = in_sizes[1] / (3 * p.B);
    p.No = in_sizes[2] / (3 * p.B);
    p.Fo = in_sizes[3] / (3 * p.B);

    p.nRangeA = (p.Fh + 63) / 64;              // 25  (64 tris per wave-range)
    p.nRangeB = (p.Fo + 63) / 64;              // 63
    p.nPSA = (p.No + PTS_PER_TASK - 1) / PTS_PER_TASK;   // 16
    p.nPSB = (p.Nh + PTS_PER_TASK - 1) / PTS_PER_TASK;   // 7
    p.taskA = p.B * p.nRangeA * p.nPSA;        // 3200
    p.taskB = p.B * p.nRangeB * p.nPSB;        // 3528
    p.nRayW = p.taskA + p.taskB;

    char* ws = (char*)d_ws;
    size_t off = 0;
    auto alloc = [&](size_t bytes) -> void* {
        void* q = ws + off;
        off = (off + bytes + 255) & ~(size_t)255;
        return q;
    };
    p.hitsA    = (int*)   alloc((size_t)p.nRangeA * p.B * p.No * sizeof(int));
    p.hitsB    = (int*)   alloc((size_t)p.nRangeB * p.B * p.Nh * sizeof(int));
    p.anchor_h = (float*) alloc((size_t)p.B * p.Nh * sizeof(float));
    p.anchor_o = (float*) alloc((size_t)p.B * p.No * sizeof(float));
    p.partials = (float*) alloc((size_t)p.B * 16 * 6 * sizeof(float));
    p.done     = (unsigned int*)alloc(sizeof(unsigned int));

    int totalMin = p.B * (p.Nh + p.No);
    int totalW   = p.nRayW + totalMin;
    int grid     = (totalW + 3) / 4;           // 4 wave-tasks per block

    mega<<<grid, 256, 0, stream>>>(p);
    reduce_fin<<<p.B * 16, 64, 0, stream>>>(p);
}

// Round 7
// 154.337 us; speedup vs baseline: 1.3679x; 1.1482x over previous
//
#include <hip/hip_runtime.h>

// ContactLoss R13: R9 structure + 4-pt raycast at FULL block count.
//  - R12 falsified the transposed (tri-per-lane) form: broadcast loop costs
//    1.7x the VALU. R9's LDS read is wave-uniform (broadcast) => cheap.
//  - R10's 4-pt failure re-diagnosed as occupancy (512 heavy blocks = 2/CU).
//    Fix: CA=32, CB=64 with PTS_PER_BLK=1024 => 1024 raycast blocks (4/CU,
//    same per-block work as R9), 4 tests per LDS tri read, quad/triple/dual/
//    single wave-uniform __any ladder (R9/R10-proven, absmax 0.0 lineage).
//  - reduce_fin: R9 verbatim (chunk counts follow CA/chunkB; integer parity).

#define RX 0.4395064455f
#define RY 0.617598629942f
#define RZ 0.652231566745f

#define MAXCHUNK_F4 512   // LDS float4 slots; >= max(chunkA,chunkB)*4
#define PTS_PER_BLK 1024  // 4 points per thread @ 256 threads

struct Params {
    const float* hand_verts; const int* hand_faces;
    const float* obj_verts;  const int* obj_faces;
    const int* ovsplit; const int* ofsplit;
    int* hitsA;                // [CA*B*No] pass-A per-chunk hit counts
    int* hitsB;                // [CB*B*Nh] pass-B per-chunk hit counts
    float* anchor_h; float* anchor_o;
    float* partials;           // [B*16*6] per-(batch, virtual-wave) partials
    unsigned int* done;
    float* out;
    int B, Nh, Fh, No, Fo;
    int pbA, CA, chunkA, blocksA;
    int pbB, CB, chunkB, blocksB;
};

// ---------------------------------------------------------------------------
// Per-triangle precompute (absmax-0.0 lineage; valid folded into invdet=0 —
// R7/R9/R10-validated bit-exact).
// ---------------------------------------------------------------------------
__device__ __forceinline__ void tri_pre_one(const float* __restrict__ vb,
                                            const int* __restrict__ f,
                                            float4* o) {
#pragma clang fp contract(off)
    int i0 = f[0], i1 = f[1], i2 = f[2];
    float v0x = vb[i0*3+0], v0y = vb[i0*3+1], v0z = vb[i0*3+2];
    float v1x = vb[i1*3+0], v1y = vb[i1*3+1], v1z = vb[i1*3+2];
    float v2x = vb[i2*3+0], v2y = vb[i2*3+1], v2z = vb[i2*3+2];
    float e1x = v1x - v0x, e1y = v1y - v0y, e1z = v1z - v0z;
    float e2x = v2x - v0x, e2y = v2y - v0y, e2z = v2z - v0z;
    float px = RY*e2z - RZ*e2y;
    float py = RZ*e2x - RX*e2z;
    float pz = RX*e2y - RY*e2x;
    float det = (e1x*px + e1y*py) + e1z*pz;       // ((a+b)+c) like np.sum
    float invdet = 1.0f / (det + 1e-8f);          // 0.1*TOL, IEEE div
    if (fabsf(det) < 1e-7f) invdet = 0.0f;        // parallel => no hit, exactly
    o[0] = make_float4(v0x, v0y, v0z, invdet);
    o[1] = make_float4(e1x, e1y, e1z, 0.0f);
    o[2] = make_float4(e2x, e2y, e2z, 0.0f);
    o[3] = make_float4(px,  py,  pz,  0.0f);
}

// One Möller–Trumbore test (expression tree identical to absmax-0.0 lineage).
__device__ __forceinline__ int mt_test(float qx, float qy, float qz,
                                       const float4& f0, const float4& f1,
                                       const float4& f2, const float4& f3) {
#pragma clang fp contract(off)
    float tvx = qx - f0.x, tvy = qy - f0.y, tvz = qz - f0.z;
    float u  = ((tvx*f3.x + tvy*f3.y) + tvz*f3.z) * f0.w;
    float qvx = tvy*f1.z - tvz*f1.y;
    float qvy = tvz*f1.x - tvx*f1.z;
    float qvz = tvx*f1.y - tvy*f1.x;
    float v  = ((qvx*RX + qvy*RY) + qvz*RZ) * f0.w;
    float tt = ((f2.x*qvx + f2.y*qvy) + f2.z*qvz) * f0.w;
    bool hit = (u > 0.0f) && (u < 1.0f) && (v > 0.0f) &&
               ((u + v) < 1.0f) && (tt > 1e-7f);
    return hit ? 1 : 0;
}

// ---------------------------------------------------------------------------
// One raycast virtual block: chunk staged in LDS; each thread tests FOUR
// points per tri read. Loop depth chosen wave-uniformly by __any over the
// monotone act masks (R9/R10-proven); discarded lanes compute exactly as
// before (stores guarded).
// ---------------------------------------------------------------------------
__device__ __forceinline__ void raycast_vb(const Params& p, int vbid, int tid,
                                           float4* s_tri) {
#pragma clang fp contract(off)
    const float* pts; const float* tverts; const int* tfaces; int* slots;
    int P, T, Nv, c, pb, b, chunk, tlim, plim;
    if (vbid < p.blocksA) {
        int per_b = p.pbA * p.CA;
        b  = vbid / per_b;
        int r = vbid - b * per_b;
        c  = r / p.pbA;
        pb = r - c * p.pbA;
        pts = p.obj_verts; tverts = p.hand_verts; tfaces = p.hand_faces;
        slots = p.hitsA;
        P = p.No; T = p.Fh; Nv = p.Nh; chunk = p.chunkA;
        tlim = p.Fh; plim = min(p.No, p.ovsplit[b]);   // invalid pts never read
    } else {
        int j = vbid - p.blocksA;
        int per_b = p.pbB * p.CB;
        b  = j / per_b;
        int r = j - b * per_b;
        c  = r / p.pbB;
        pb = r - c * p.pbB;
        pts = p.hand_verts; tverts = p.obj_verts; tfaces = p.obj_faces;
        slots = p.hitsB;
        P = p.Nh; T = p.Fo; Nv = p.No; chunk = p.chunkB;
        tlim = min(p.Fo, p.ofsplit[b]); plim = p.Nh;
    }

    int tStart = c * chunk;
    if (tStart >= tlim) return;               // block-uniform (slots unread)
    if (pb * PTS_PER_BLK >= plim) return;     // block-uniform (slots unread)
    int nTri = min(tStart + chunk, tlim) - tStart;

    if (tid < nTri) {
        int t = tStart + tid;
        tri_pre_one(tverts + (size_t)b * Nv * 3,
                    tfaces + ((size_t)b * T + t) * 3,
                    s_tri + (size_t)tid * 4);
    }

    int p1 = pb * PTS_PER_BLK + tid;
    int p2 = p1 + 256, p3 = p1 + 512, p4 = p1 + 768;
    bool act1 = p1 < plim, act2 = p2 < plim, act3 = p3 < plim, act4 = p4 < plim;
    float q1x=0.f,q1y=0.f,q1z=0.f, q2x=0.f,q2y=0.f,q2z=0.f;
    float q3x=0.f,q3y=0.f,q3z=0.f, q4x=0.f,q4y=0.f,q4z=0.f;
    if (act1) { const float* q = pts + ((size_t)b*P + p1)*3; q1x=q[0]; q1y=q[1]; q1z=q[2]; }
    if (act2) { const float* q = pts + ((size_t)b*P + p2)*3; q2x=q[0]; q2y=q[1]; q2z=q[2]; }
    if (act3) { const float* q = pts + ((size_t)b*P + p3)*3; q3x=q[0]; q3y=q[1]; q3z=q[2]; }
    if (act4) { const float* q = pts + ((size_t)b*P + p4)*3; q4x=q[0]; q4y=q[1]; q4z=q[2]; }
    __syncthreads();

    if (!act1) return;                        // act masks are monotone
    int c1=0, c2=0, c3=0, c4=0;
    if (__any(act4)) {
        for (int i = 0; i < nTri; ++i) {
            const float4 f0 = s_tri[(i<<2)+0];
            const float4 f1 = s_tri[(i<<2)+1];
            const float4 f2 = s_tri[(i<<2)+2];
            const float4 f3 = s_tri[(i<<2)+3];
            c1 += mt_test(q1x,q1y,q1z, f0,f1,f2,f3);
            c2 += mt_test(q2x,q2y,q2z, f0,f1,f2,f3);
            c3 += mt_test(q3x,q3y,q3z, f0,f1,f2,f3);
            c4 += mt_test(q4x,q4y,q4z, f0,f1,f2,f3);
        }
    } else if (__any(act3)) {
        for (int i = 0; i < nTri; ++i) {
            const float4 f0 = s_tri[(i<<2)+0];
            const float4 f1 = s_tri[(i<<2)+1];
            const float4 f2 = s_tri[(i<<2)+2];
            const float4 f3 = s_tri[(i<<2)+3];
            c1 += mt_test(q1x,q1y,q1z, f0,f1,f2,f3);
            c2 += mt_test(q2x,q2y,q2z, f0,f1,f2,f3);
            c3 += mt_test(q3x,q3y,q3z, f0,f1,f2,f3);
        }
    } else if (__any(act2)) {
        for (int i = 0; i < nTri; ++i) {
            const float4 f0 = s_tri[(i<<2)+0];
            const float4 f1 = s_tri[(i<<2)+1];
            const float4 f2 = s_tri[(i<<2)+2];
            const float4 f3 = s_tri[(i<<2)+3];
            c1 += mt_test(q1x,q1y,q1z, f0,f1,f2,f3);
            c2 += mt_test(q2x,q2y,q2z, f0,f1,f2,f3);
        }
    } else {
        for (int i = 0; i < nTri; ++i) {
            const float4 f0 = s_tri[(i<<2)+0];
            const float4 f1 = s_tri[(i<<2)+1];
            const float4 f2 = s_tri[(i<<2)+2];
            const float4 f3 = s_tri[(i<<2)+3];
            c1 += mt_test(q1x,q1y,q1z, f0,f1,f2,f3);
        }
    }
    int* base = slots + ((size_t)(c * p.B + b)) * P;
    base[p1] = c1;                            // plain stores, no atomics
    if (act2) base[p2] = c2;
    if (act3) base[p3] = c3;
    if (act4) base[p4] = c4;
}

// ---------------------------------------------------------------------------
// One argmin wave. Packed (dist<<32)|idx min => np.argmin tie-break.
// ---------------------------------------------------------------------------
__device__ __forceinline__ void min_one(const Params& p, int w, int lane) {
#pragma clang fp contract(off)
    int nHand = p.B * p.Nh;
    const float* refv; const float* loopv; int loopN; float* outp;
    if (w < nHand) {
        int b = w / p.Nh;
        int n = w - b * p.Nh;
        refv  = p.hand_verts + ((size_t)b * p.Nh + n) * 3;
        loopv = p.obj_verts + (size_t)b * p.No * 3;
        loopN = p.ovsplit[b];
        outp  = p.anchor_h + (size_t)b * p.Nh + n;
    } else {
        int j = w - nHand;
        int b = j / p.No;
        int m = j - b * p.No;
        if (m >= p.ovsplit[b]) return;
        refv  = p.obj_verts + ((size_t)b * p.No + m) * 3;
        loopv = p.hand_verts + (size_t)b * p.Nh * 3;
        loopN = p.Nh;
        outp  = p.anchor_o + (size_t)b * p.No + m;
    }
    float hx = refv[0], hy = refv[1], hz = refv[2];
    float rx = (hx*hx + hy*hy) + hz*hz;
    unsigned long long best = ~0ull;
    for (int m = lane; m < loopN; m += 64) {
        float ox = loopv[m*3+0], oy = loopv[m*3+1], oz = loopv[m*3+2];
        float ry = (ox*ox + oy*oy) + oz*oz;
        float zz = (hx*ox + hy*oy) + hz*oz;
        float d = (rx + ry) - 2.0f * zz;
        unsigned long long e = ((unsigned long long)__float_as_uint(d) << 32) | (unsigned)m;
        if (e < best) best = e;
    }
    for (int off = 32; off > 0; off >>= 1) {
        unsigned long long o = __shfl_xor(best, off, 64);
        if (o < best) best = o;
    }
    if (lane == 0) {
        int idx = (best == ~0ull) ? 0 : (int)(best & 0xffffffffu);
        const float* cv = loopv + (size_t)idx * 3;
        float dx = cv[0] - hx, dy = cv[1] - hy, dz = cv[2] - hz;
        *outp = sqrtf((dx*dx + dy*dy) + dz*dz);
    }
}

// ---------------------------------------------------------------------------
// mega: [raycast VBs | argmin blocks] — no tail sync; resets done counter.
// ---------------------------------------------------------------------------
__global__ __launch_bounds__(256) void mega(Params p) {
    __shared__ float4 s_tri[MAXCHUNK_F4];
    const int tid = threadIdx.x;
    const int bid = blockIdx.x;
    if (bid == 0 && tid == 0) *p.done = 0u;   // visible to reduce_fin at boundary
    const int nRay = p.blocksA + p.blocksB;
    if (bid < nRay) {
        raycast_vb(p, bid, tid, s_tri);
    } else {
        int w = (bid - nRay) * 4 + (tid >> 6);
        if (w < p.B * (p.Nh + p.No)) min_one(p, w, tid & 63);
    }
}

// ---------------------------------------------------------------------------
// reduce_fin: 128 single-wave blocks (R8/R9 verbatim). Block r = (batch
// b=r>>4, virtual wave wv=r&15) of the old 1024-thread tree; bit-exact
// decomposition; done-counter + fence finalize.
// ---------------------------------------------------------------------------
__global__ __launch_bounds__(64) void reduce_fin(Params p) {
    const int r    = blockIdx.x;
    const int b    = r >> 4;
    const int wv   = r & 15;
    const int lane = threadIdx.x;
    const int vt   = wv * 64 + lane;          // virtual tid 0..1023
    float s0=0.f,s1=0.f,s2=0.f,s3=0.f,s4=0.f,s5=0.f;

    int tlimB = min(p.Fo, p.ofsplit[b]);
    int nCB = (tlimB + p.chunkB - 1) / p.chunkB;        // valid pass-B chunks
    for (int n = vt; n < p.Nh; n += 1024) {
        int par = 0;
        for (int c = 0; c < nCB; ++c)
            par += p.hitsB[((size_t)(c * p.B + b)) * p.Nh + n];
        bool ext = (par & 1) == 0;
        float val = 25.0f * tanhf(p.anchor_h[(size_t)b*p.Nh + n] / 25.0f);
        if (ext) { s0 += val; s1 += 1.0f; } else { s2 += val; s3 += 1.0f; }
    }
    int split = p.ovsplit[b];
    for (int m = vt; m < split; m += 1024) {
        int par = 0;
        for (int c = 0; c < p.CA; ++c)
            par += p.hitsA[((size_t)(c * p.B + b)) * p.No + m];
        if (par & 1) {                                   // interior & valid
            s4 += 25.0f * tanhf(p.anchor_o[(size_t)b*p.No + m] / 25.0f);
            s5 += 1.0f;
        }
    }
    for (int off = 32; off > 0; off >>= 1) {
        s0 += __shfl_xor(s0, off, 64);
        s1 += __shfl_xor(s1, off, 64);
        s2 += __shfl_xor(s2, off, 64);
        s3 += __shfl_xor(s3, off, 64);
        s4 += __shfl_xor(s4, off, 64);
        s5 += __shfl_xor(s5, off, 64);
    }

    __shared__ bool s_last;
    if (lane == 0) {
        float* q = p.partials + ((size_t)(b * 16 + wv)) * 6;
        q[0]=s0; q[1]=s1; q[2]=s2; q[3]=s3; q[4]=s4; q[5]=s5;
        __threadfence();                     // release partials
        unsigned int old = atomicAdd(p.done, 1u);
        s_last = (old == (unsigned int)(gridDim.x - 1));
    }
    __syncthreads();
    if (!s_last) return;
    __threadfence();                         // acquire others' partials

    __shared__ float s_red[16][6];
    if (lane < p.B && lane < 16) {
        int bb = lane;
        float t0=0.f,t1=0.f,t2=0.f,t3=0.f,t4=0.f,t5=0.f;
        for (int w2 = 0; w2 < 16; ++w2) {     // same wave order as old loop
            const float* q = p.partials + ((size_t)(bb * 16 + w2)) * 6;
            t0 += q[0]; t1 += q[1]; t2 += q[2];
            t3 += q[3]; t4 += q[4]; t5 += q[5];
        }
        p.out[2 + bb]  = (t1 > 0.f) ? t0 / fmaxf(t1, 1.f) : 0.f;
        float ph       = (t3 > 0.f) ? t2 / fmaxf(t3, 1.f) : 0.f;
        float po       = (t5 > 0.f) ? t4 / fmaxf(t5, 1.f) : 0.f;
        p.out[10 + bb] = ph + po;
        s_red[bb][0]=t0; s_red[bb][1]=t1; s_red[bb][2]=t2;
        s_red[bb][3]=t3; s_red[bb][4]=t4; s_red[bb][5]=t5;
    }
    __syncthreads();
    if (lane == 0) {
        float sm=0.f,cm=0.f,sph=0.f,cph=0.f,spo=0.f,cpo=0.f;
        for (int bb = 0; bb < p.B; ++bb) {    // same batch order as old final
            sm  += s_red[bb][0]; cm  += s_red[bb][1]; sph += s_red[bb][2];
            cph += s_red[bb][3]; spo += s_red[bb][4]; cpo += s_red[bb][5];
        }
        float missed = (cm  > 0.f) ? sm  / fmaxf(cm , 1.f) : 0.f;
        float ph     = (cph > 0.f) ? sph / fmaxf(cph, 1.f) : 0.f;
        float po     = (cpo > 0.f) ? spo / fmaxf(cpo, 1.f) : 0.f;
        p.out[0] = missed;
        p.out[1] = ph + po;
    }
}

// ---------------------------------------------------------------------------
extern "C" void kernel_launch(void* const* d_in, const int* in_sizes, int n_in,
                              void* d_out, int out_size, void* d_ws, size_t ws_size,
                              hipStream_t stream) {
    Params p;
    p.hand_verts = (const float*)d_in[0];
    p.hand_faces = (const int*)d_in[1];
    p.obj_verts  = (const float*)d_in[2];
    p.obj_faces  = (const int*)d_in[3];
    p.ovsplit    = (const int*)d_in[4];
    p.ofsplit    = (const int*)d_in[5];
    p.out        = (float*)d_out;

    p.B  = in_sizes[4];
    p.Nh = in_sizes[0] / (3 * p.B);
    p.Fh = in_sizes[1] / (3 * p.B);
    p.No = in_sizes[2] / (3 * p.B);
    p.Fo = in_sizes[3] / (3 * p.B);

    p.CA = 32; p.CB = 64;
    p.chunkA = (p.Fh + p.CA - 1) / p.CA;       // 49 for Fh=1538 (196 f4 <= 512)
    p.chunkB = (p.Fo + p.CB - 1) / p.CB;       // 63 for Fo=4000 (252 f4 <= 512)
    p.pbA = (p.No + PTS_PER_BLK - 1) / PTS_PER_BLK;   // 2
    p.pbB = (p.Nh + PTS_PER_BLK - 1) / PTS_PER_BLK;   // 1
    p.blocksA = p.pbA * p.CA * p.B;            // 512
    p.blocksB = p.pbB * p.CB * p.B;            // 512

    char* ws = (char*)d_ws;
    size_t off = 0;
    auto alloc = [&](size_t bytes) -> void* {
        void* q = ws + off;
        off = (off + bytes + 255) & ~(size_t)255;
        return q;
    };
    p.hitsA    = (int*)   alloc((size_t)p.CA * p.B * p.No * sizeof(int));
    p.hitsB    = (int*)   alloc((size_t)p.CB * p.B * p.Nh * sizeof(int));
    p.anchor_h = (float*) alloc((size_t)p.B * p.Nh * sizeof(float));
    p.anchor_o = (float*) alloc((size_t)p.B * p.No * sizeof(float));
    p.partials = (float*) alloc((size_t)p.B * 16 * 6 * sizeof(float));
    p.done     = (unsigned int*)alloc(sizeof(unsigned int));

    int totalMin   = p.B * (p.Nh + p.No);
    int nMinBlocks = (totalMin + 3) / 4;       // 4 argmin waves per block
    int grid = p.blocksA + p.blocksB + nMinBlocks;

    mega<<<grid, 256, 0, stream>>>(p);
    reduce_fin<<<p.B * 16, 64, 0, stream>>>(p);
}

// Round 8
// 140.506 us; speedup vs baseline: 1.5025x; 1.0984x over previous
//
#include <hip/hip_runtime.h>

// ContactLoss R14: R9 body VERBATIM with a finer heavy-block partition.
//  - R13 falsified 4-pt (VGPR 68 halves occupancy; -3.5us instr, +13us stall).
//  - R9's occupancy ceiling was BLOCK SUPPLY: 1024 heavy blocks = 4/CU = 16
//    waves (54% measured). CA=32/CB=64 @ PTS=512 => 2048 heavy blocks = 8/CU
//    (VGPR 32 and 4KB LDS both allow it), same total work/staging/arithmetic.
//  - reduce_fin: R9 verbatim (parity loops follow CA/chunkB; integer-exact).

#define RX 0.4395064455f
#define RY 0.617598629942f
#define RZ 0.652231566745f

#define MAXCHUNK_F4 256   // LDS float4 slots; >= max(chunkA,chunkB)*4 (252)
#define PTS_PER_BLK 512   // 2 points per thread

struct Params {
    const float* hand_verts; const int* hand_faces;
    const float* obj_verts;  const int* obj_faces;
    const int* ovsplit; const int* ofsplit;
    int* hitsA;                // [CA*B*No] pass-A per-chunk hit counts
    int* hitsB;                // [CB*B*Nh] pass-B per-chunk hit counts
    float* anchor_h; float* anchor_o;
    float* partials;           // [B*16*6] per-(batch, virtual-wave) partials
    unsigned int* done;
    float* out;
    int B, Nh, Fh, No, Fo;
    int pbA, CA, chunkA, blocksA;
    int pbB, CB, chunkB, blocksB;
};

// ---------------------------------------------------------------------------
// Per-triangle precompute (absmax-0.0 lineage; valid folded into invdet=0 —
// R7/R9-validated bit-exact).
// ---------------------------------------------------------------------------
__device__ __forceinline__ void tri_pre_one(const float* __restrict__ vb,
                                            const int* __restrict__ f,
                                            float4* o) {
#pragma clang fp contract(off)
    int i0 = f[0], i1 = f[1], i2 = f[2];
    float v0x = vb[i0*3+0], v0y = vb[i0*3+1], v0z = vb[i0*3+2];
    float v1x = vb[i1*3+0], v1y = vb[i1*3+1], v1z = vb[i1*3+2];
    float v2x = vb[i2*3+0], v2y = vb[i2*3+1], v2z = vb[i2*3+2];
    float e1x = v1x - v0x, e1y = v1y - v0y, e1z = v1z - v0z;
    float e2x = v2x - v0x, e2y = v2y - v0y, e2z = v2z - v0z;
    float px = RY*e2z - RZ*e2y;
    float py = RZ*e2x - RX*e2z;
    float pz = RX*e2y - RY*e2x;
    float det = (e1x*px + e1y*py) + e1z*pz;       // ((a+b)+c) like np.sum
    float invdet = 1.0f / (det + 1e-8f);          // 0.1*TOL, IEEE div
    if (fabsf(det) < 1e-7f) invdet = 0.0f;        // parallel => no hit, exactly
    o[0] = make_float4(v0x, v0y, v0z, invdet);
    o[1] = make_float4(e1x, e1y, e1z, 0.0f);
    o[2] = make_float4(e2x, e2y, e2z, 0.0f);
    o[3] = make_float4(px,  py,  pz,  0.0f);
}

// One Möller–Trumbore test (expression tree identical to absmax-0.0 lineage).
__device__ __forceinline__ int mt_test(float qx, float qy, float qz,
                                       const float4& f0, const float4& f1,
                                       const float4& f2, const float4& f3) {
#pragma clang fp contract(off)
    float tvx = qx - f0.x, tvy = qy - f0.y, tvz = qz - f0.z;
    float u  = ((tvx*f3.x + tvy*f3.y) + tvz*f3.z) * f0.w;
    float qvx = tvy*f1.z - tvz*f1.y;
    float qvy = tvz*f1.x - tvx*f1.z;
    float qvz = tvx*f1.y - tvy*f1.x;
    float v  = ((qvx*RX + qvy*RY) + qvz*RZ) * f0.w;
    float tt = ((f2.x*qvx + f2.y*qvy) + f2.z*qvz) * f0.w;
    bool hit = (u > 0.0f) && (u < 1.0f) && (v > 0.0f) &&
               ((u + v) < 1.0f) && (tt > 1e-7f);
    return hit ? 1 : 0;
}

// ---------------------------------------------------------------------------
// One raycast virtual block: triangle chunk built inline into LDS, each
// thread tests TWO points. Wave-uniform __any(act2) loop selection
// (R9-proven; discarded lanes compute exactly as before, stores guarded).
// ---------------------------------------------------------------------------
__device__ __forceinline__ void raycast_vb(const Params& p, int vbid, int tid,
                                           float4* s_tri) {
#pragma clang fp contract(off)
    const float* pts; const float* tverts; const int* tfaces; int* slots;
    int P, T, Nv, c, pb, b, chunk, tlim, plim;
    if (vbid < p.blocksA) {
        int per_b = p.pbA * p.CA;
        b  = vbid / per_b;
        int r = vbid - b * per_b;
        c  = r / p.pbA;
        pb = r - c * p.pbA;
        pts = p.obj_verts; tverts = p.hand_verts; tfaces = p.hand_faces;
        slots = p.hitsA;
        P = p.No; T = p.Fh; Nv = p.Nh; chunk = p.chunkA;
        tlim = p.Fh; plim = min(p.No, p.ovsplit[b]);   // invalid pts never read
    } else {
        int j = vbid - p.blocksA;
        int per_b = p.pbB * p.CB;
        b  = j / per_b;
        int r = j - b * per_b;
        c  = r / p.pbB;
        pb = r - c * p.pbB;
        pts = p.hand_verts; tverts = p.obj_verts; tfaces = p.obj_faces;
        slots = p.hitsB;
        P = p.Nh; T = p.Fo; Nv = p.No; chunk = p.chunkB;
        tlim = min(p.Fo, p.ofsplit[b]); plim = p.Nh;
    }

    int tStart = c * chunk;
    if (tStart >= tlim) return;               // block-uniform (slots unread)
    if (pb * PTS_PER_BLK >= plim) return;     // block-uniform (slots unread)
    int nTri = min(tStart + chunk, tlim) - tStart;

    if (tid < nTri) {
        int t = tStart + tid;
        tri_pre_one(tverts + (size_t)b * Nv * 3,
                    tfaces + ((size_t)b * T + t) * 3,
                    s_tri + (size_t)tid * 4);
    }

    int p1 = pb * PTS_PER_BLK + tid;
    int p2 = p1 + 256;
    bool act1 = p1 < plim, act2 = p2 < plim;
    float q1x = 0.f, q1y = 0.f, q1z = 0.f;
    float q2x = 0.f, q2y = 0.f, q2z = 0.f;
    if (act1) {
        const float* q = pts + ((size_t)b * P + p1) * 3;
        q1x = q[0]; q1y = q[1]; q1z = q[2];
    }
    if (act2) {
        const float* q = pts + ((size_t)b * P + p2) * 3;
        q2x = q[0]; q2y = q[1]; q2z = q[2];
    }
    __syncthreads();

    if (!act1) return;                        // act1 false => act2 false
    int cnt1 = 0, cnt2 = 0;
    if (__any(act2)) {
        // Dual-point loop: identical to R9 codegen; act2-false lanes
        // compute-and-discard cnt2 exactly as before (store is guarded).
        for (int i = 0; i < nTri; ++i) {
            const float4 f0 = s_tri[(i<<2)+0];
            const float4 f1 = s_tri[(i<<2)+1];
            const float4 f2 = s_tri[(i<<2)+2];
            const float4 f3 = s_tri[(i<<2)+3];
            cnt1 += mt_test(q1x, q1y, q1z, f0, f1, f2, f3);
            cnt2 += mt_test(q2x, q2y, q2z, f0, f1, f2, f3);
        }
    } else {
        // No live second point anywhere in this wave: half the work.
        for (int i = 0; i < nTri; ++i) {
            const float4 f0 = s_tri[(i<<2)+0];
            const float4 f1 = s_tri[(i<<2)+1];
            const float4 f2 = s_tri[(i<<2)+2];
            const float4 f3 = s_tri[(i<<2)+3];
            cnt1 += mt_test(q1x, q1y, q1z, f0, f1, f2, f3);
        }
    }
    int* base = slots + ((size_t)(c * p.B + b)) * P;
    base[p1] = cnt1;                          // plain stores, no atomics
    if (act2) base[p2] = cnt2;
}

// ---------------------------------------------------------------------------
// One argmin wave. Packed (dist<<32)|idx min => np.argmin tie-break.
// ---------------------------------------------------------------------------
__device__ __forceinline__ void min_one(const Params& p, int w, int lane) {
#pragma clang fp contract(off)
    int nHand = p.B * p.Nh;
    const float* refv; const float* loopv; int loopN; float* outp;
    if (w < nHand) {
        int b = w / p.Nh;
        int n = w - b * p.Nh;
        refv  = p.hand_verts + ((size_t)b * p.Nh + n) * 3;
        loopv = p.obj_verts + (size_t)b * p.No * 3;
        loopN = p.ovsplit[b];
        outp  = p.anchor_h + (size_t)b * p.Nh + n;
    } else {
        int j = w - nHand;
        int b = j / p.No;
        int m = j - b * p.No;
        if (m >= p.ovsplit[b]) return;
        refv  = p.obj_verts + ((size_t)b * p.No + m) * 3;
        loopv = p.hand_verts + (size_t)b * p.Nh * 3;
        loopN = p.Nh;
        outp  = p.anchor_o + (size_t)b * p.No + m;
    }
    float hx = refv[0], hy = refv[1], hz = refv[2];
    float rx = (hx*hx + hy*hy) + hz*hz;
    unsigned long long best = ~0ull;
    for (int m = lane; m < loopN; m += 64) {
        float ox = loopv[m*3+0], oy = loopv[m*3+1], oz = loopv[m*3+2];
        float ry = (ox*ox + oy*oy) + oz*oz;
        float zz = (hx*ox + hy*oy) + hz*oz;
        float d = (rx + ry) - 2.0f * zz;
        unsigned long long e = ((unsigned long long)__float_as_uint(d) << 32) | (unsigned)m;
        if (e < best) best = e;
    }
    for (int off = 32; off > 0; off >>= 1) {
        unsigned long long o = __shfl_xor(best, off, 64);
        if (o < best) best = o;
    }
    if (lane == 0) {
        int idx = (best == ~0ull) ? 0 : (int)(best & 0xffffffffu);
        const float* cv = loopv + (size_t)idx * 3;
        float dx = cv[0] - hx, dy = cv[1] - hy, dz = cv[2] - hz;
        *outp = sqrtf((dx*dx + dy*dy) + dz*dz);
    }
}

// ---------------------------------------------------------------------------
// mega: [raycast VBs | argmin blocks] — no tail sync; resets done counter.
// ---------------------------------------------------------------------------
__global__ __launch_bounds__(256) void mega(Params p) {
    __shared__ float4 s_tri[MAXCHUNK_F4];
    const int tid = threadIdx.x;
    const int bid = blockIdx.x;
    if (bid == 0 && tid == 0) *p.done = 0u;   // visible to reduce_fin at boundary
    const int nRay = p.blocksA + p.blocksB;
    if (bid < nRay) {
        raycast_vb(p, bid, tid, s_tri);
    } else {
        int w = (bid - nRay) * 4 + (tid >> 6);
        if (w < p.B * (p.Nh + p.No)) min_one(p, w, tid & 63);
    }
}

// ---------------------------------------------------------------------------
// reduce_fin: 128 single-wave blocks (R8/R9 verbatim). Block r = (batch
// b=r>>4, virtual wave wv=r&15) of the old 1024-thread tree; bit-exact
// decomposition; done-counter + fence finalize.
// ---------------------------------------------------------------------------
__global__ __launch_bounds__(64) void reduce_fin(Params p) {
    const int r    = blockIdx.x;
    const int b    = r >> 4;
    const int wv   = r & 15;
    const int lane = threadIdx.x;
    const int vt   = wv * 64 + lane;          // virtual tid 0..1023
    float s0=0.f,s1=0.f,s2=0.f,s3=0.f,s4=0.f,s5=0.f;

    int tlimB = min(p.Fo, p.ofsplit[b]);
    int nCB = (tlimB + p.chunkB - 1) / p.chunkB;        // valid pass-B chunks
    for (int n = vt; n < p.Nh; n += 1024) {
        int par = 0;
        for (int c = 0; c < nCB; ++c)
            par += p.hitsB[((size_t)(c * p.B + b)) * p.Nh + n];
        bool ext = (par & 1) == 0;
        float val = 25.0f * tanhf(p.anchor_h[(size_t)b*p.Nh + n] / 25.0f);
        if (ext) { s0 += val; s1 += 1.0f; } else { s2 += val; s3 += 1.0f; }
    }
    int split = p.ovsplit[b];
    for (int m = vt; m < split; m += 1024) {
        int par = 0;
        for (int c = 0; c < p.CA; ++c)
            par += p.hitsA[((size_t)(c * p.B + b)) * p.No + m];
        if (par & 1) {                                   // interior & valid
            s4 += 25.0f * tanhf(p.anchor_o[(size_t)b*p.No + m] / 25.0f);
            s5 += 1.0f;
        }
    }
    for (int off = 32; off > 0; off >>= 1) {
        s0 += __shfl_xor(s0, off, 64);
        s1 += __shfl_xor(s1, off, 64);
        s2 += __shfl_xor(s2, off, 64);
        s3 += __shfl_xor(s3, off, 64);
        s4 += __shfl_xor(s4, off, 64);
        s5 += __shfl_xor(s5, off, 64);
    }

    __shared__ bool s_last;
    if (lane == 0) {
        float* q = p.partials + ((size_t)(b * 16 + wv)) * 6;
        q[0]=s0; q[1]=s1; q[2]=s2; q[3]=s3; q[4]=s4; q[5]=s5;
        __threadfence();                     // release partials
        unsigned int old = atomicAdd(p.done, 1u);
        s_last = (old == (unsigned int)(gridDim.x - 1));
    }
    __syncthreads();
    if (!s_last) return;
    __threadfence();                         // acquire others' partials

    __shared__ float s_red[16][6];
    if (lane < p.B && lane < 16) {
        int bb = lane;
        float t0=0.f,t1=0.f,t2=0.f,t3=0.f,t4=0.f,t5=0.f;
        for (int w2 = 0; w2 < 16; ++w2) {     // same wave order as old loop
            const float* q = p.partials + ((size_t)(bb * 16 + w2)) * 6;
            t0 += q[0]; t1 += q[1]; t2 += q[2];
            t3 += q[3]; t4 += q[4]; t5 += q[5];
        }
        p.out[2 + bb]  = (t1 > 0.f) ? t0 / fmaxf(t1, 1.f) : 0.f;
        float ph       = (t3 > 0.f) ? t2 / fmaxf(t3, 1.f) : 0.f;
        float po       = (t5 > 0.f) ? t4 / fmaxf(t5, 1.f) : 0.f;
        p.out[10 + bb] = ph + po;
        s_red[bb][0]=t0; s_red[bb][1]=t1; s_red[bb][2]=t2;
        s_red[bb][3]=t3; s_red[bb][4]=t4; s_red[bb][5]=t5;
    }
    __syncthreads();
    if (lane == 0) {
        float sm=0.f,cm=0.f,sph=0.f,cph=0.f,spo=0.f,cpo=0.f;
        for (int bb = 0; bb < p.B; ++bb) {    // same batch order as old final
            sm  += s_red[bb][0]; cm  += s_red[bb][1]; sph += s_red[bb][2];
            cph += s_red[bb][3]; spo += s_red[bb][4]; cpo += s_red[bb][5];
        }
        float missed = (cm  > 0.f) ? sm  / fmaxf(cm , 1.f) : 0.f;
        float ph     = (cph > 0.f) ? sph / fmaxf(cph, 1.f) : 0.f;
        float po     = (cpo > 0.f) ? spo / fmaxf(cpo, 1.f) : 0.f;
        p.out[0] = missed;
        p.out[1] = ph + po;
    }
}

// ---------------------------------------------------------------------------
extern "C" void kernel_launch(void* const* d_in, const int* in_sizes, int n_in,
                              void* d_out, int out_size, void* d_ws, size_t ws_size,
                              hipStream_t stream) {
    Params p;
    p.hand_verts = (const float*)d_in[0];
    p.hand_faces = (const int*)d_in[1];
    p.obj_verts  = (const float*)d_in[2];
    p.obj_faces  = (const int*)d_in[3];
    p.ovsplit    = (const int*)d_in[4];
    p.ofsplit    = (const int*)d_in[5];
    p.out        = (float*)d_out;

    p.B  = in_sizes[4];
    p.Nh = in_sizes[0] / (3 * p.B);
    p.Fh = in_sizes[1] / (3 * p.B);
    p.No = in_sizes[2] / (3 * p.B);
    p.Fo = in_sizes[3] / (3 * p.B);

    p.CA = 32; p.CB = 64;
    p.chunkA = (p.Fh + p.CA - 1) / p.CA;       // 49 for Fh=1538 (196 f4 <= 256)
    p.chunkB = (p.Fo + p.CB - 1) / p.CB;       // 63 for Fo=4000 (252 f4 <= 256)
    p.pbA = (p.No + PTS_PER_BLK - 1) / PTS_PER_BLK;   // 4
    p.pbB = (p.Nh + PTS_PER_BLK - 1) / PTS_PER_BLK;   // 2
    p.blocksA = p.pbA * p.CA * p.B;            // 1024
    p.blocksB = p.pbB * p.CB * p.B;            // 1024

    char* ws = (char*)d_ws;
    size_t off = 0;
    auto alloc = [&](size_t bytes) -> void* {
        void* q = ws + off;
        off = (off + bytes + 255) & ~(size_t)255;
        return q;
    };
    p.hitsA    = (int*)   alloc((size_t)p.CA * p.B * p.No * sizeof(int));
    p.hitsB    = (int*)   alloc((size_t)p.CB * p.B * p.Nh * sizeof(int));
    p.anchor_h = (float*) alloc((size_t)p.B * p.Nh * sizeof(float));
    p.anchor_o = (float*) alloc((size_t)p.B * p.No * sizeof(float));
    p.partials = (float*) alloc((size_t)p.B * 16 * 6 * sizeof(float));
    p.done     = (unsigned int*)alloc(sizeof(unsigned int));

    int totalMin   = p.B * (p.Nh + p.No);
    int nMinBlocks = (totalMin + 3) / 4;       // 4 argmin waves per block
    int grid = p.blocksA + p.blocksB + nMinBlocks;

    mega<<<grid, 256, 0, stream>>>(p);
    reduce_fin<<<p.B * 16, 64, 0, stream>>>(p);
}

// Round 9
// 122.336 us; speedup vs baseline: 1.7257x; 1.1485x over previous
//
#include <hip/hip_runtime.h>

// ContactLoss R15: R14 mega (2048 heavy blocks, best measured 60.7us) +
// DECOUPLED parity: chunk blocks atomicAdd into ONE int slot per point
// (integer sum => order-independent, bit-exact). reduce_fin parity is now
// 1 load/point and independent of the mega partition. Hits arrays zeroed
// by a hipMemsetAsync node (R10 proved extra memset adds no fixed overhead).

#define RX 0.4395064455f
#define RY 0.617598629942f
#define RZ 0.652231566745f

#define MAXCHUNK_F4 256   // LDS float4 slots; >= max(chunkA,chunkB)*4 (252)
#define PTS_PER_BLK 512   // 2 points per thread

struct Params {
    const float* hand_verts; const int* hand_faces;
    const float* obj_verts;  const int* obj_faces;
    const int* ovsplit; const int* ofsplit;
    int* hitsA;                // [B*No] pass-A hit counts (atomic accum)
    int* hitsB;                // [B*Nh] pass-B hit counts (atomic accum)
    float* anchor_h; float* anchor_o;
    float* partials;           // [B*16*6] per-(batch, virtual-wave) partials
    unsigned int* done;
    float* out;
    int B, Nh, Fh, No, Fo;
    int pbA, CA, chunkA, blocksA;
    int pbB, CB, chunkB, blocksB;
};

// ---------------------------------------------------------------------------
// Per-triangle precompute (absmax-0.0 lineage; valid folded into invdet=0 —
// R7/R9-validated bit-exact).
// ---------------------------------------------------------------------------
__device__ __forceinline__ void tri_pre_one(const float* __restrict__ vb,
                                            const int* __restrict__ f,
                                            float4* o) {
#pragma clang fp contract(off)
    int i0 = f[0], i1 = f[1], i2 = f[2];
    float v0x = vb[i0*3+0], v0y = vb[i0*3+1], v0z = vb[i0*3+2];
    float v1x = vb[i1*3+0], v1y = vb[i1*3+1], v1z = vb[i1*3+2];
    float v2x = vb[i2*3+0], v2y = vb[i2*3+1], v2z = vb[i2*3+2];
    float e1x = v1x - v0x, e1y = v1y - v0y, e1z = v1z - v0z;
    float e2x = v2x - v0x, e2y = v2y - v0y, e2z = v2z - v0z;
    float px = RY*e2z - RZ*e2y;
    float py = RZ*e2x - RX*e2z;
    float pz = RX*e2y - RY*e2x;
    float det = (e1x*px + e1y*py) + e1z*pz;       // ((a+b)+c) like np.sum
    float invdet = 1.0f / (det + 1e-8f);          // 0.1*TOL, IEEE div
    if (fabsf(det) < 1e-7f) invdet = 0.0f;        // parallel => no hit, exactly
    o[0] = make_float4(v0x, v0y, v0z, invdet);
    o[1] = make_float4(e1x, e1y, e1z, 0.0f);
    o[2] = make_float4(e2x, e2y, e2z, 0.0f);
    o[3] = make_float4(px,  py,  pz,  0.0f);
}

// One Möller–Trumbore test (expression tree identical to absmax-0.0 lineage).
__device__ __forceinline__ int mt_test(float qx, float qy, float qz,
                                       const float4& f0, const float4& f1,
                                       const float4& f2, const float4& f3) {
#pragma clang fp contract(off)
    float tvx = qx - f0.x, tvy = qy - f0.y, tvz = qz - f0.z;
    float u  = ((tvx*f3.x + tvy*f3.y) + tvz*f3.z) * f0.w;
    float qvx = tvy*f1.z - tvz*f1.y;
    float qvy = tvz*f1.x - tvx*f1.z;
    float qvz = tvx*f1.y - tvy*f1.x;
    float v  = ((qvx*RX + qvy*RY) + qvz*RZ) * f0.w;
    float tt = ((f2.x*qvx + f2.y*qvy) + f2.z*qvz) * f0.w;
    bool hit = (u > 0.0f) && (u < 1.0f) && (v > 0.0f) &&
               ((u + v) < 1.0f) && (tt > 1e-7f);
    return hit ? 1 : 0;
}

// ---------------------------------------------------------------------------
// One raycast virtual block: triangle chunk built inline into LDS, each
// thread tests TWO points. Wave-uniform __any(act2) loop selection
// (R9-proven). Counts accumulate via integer atomicAdd (order-independent,
// exact); zero counts skip the atomic entirely.
// ---------------------------------------------------------------------------
__device__ __forceinline__ void raycast_vb(const Params& p, int vbid, int tid,
                                           float4* s_tri) {
#pragma clang fp contract(off)
    const float* pts; const float* tverts; const int* tfaces; int* slots;
    int P, T, Nv, c, pb, b, chunk, tlim, plim;
    if (vbid < p.blocksA) {
        int per_b = p.pbA * p.CA;
        b  = vbid / per_b;
        int r = vbid - b * per_b;
        c  = r / p.pbA;
        pb = r - c * p.pbA;
        pts = p.obj_verts; tverts = p.hand_verts; tfaces = p.hand_faces;
        slots = p.hitsA;
        P = p.No; T = p.Fh; Nv = p.Nh; chunk = p.chunkA;
        tlim = p.Fh; plim = min(p.No, p.ovsplit[b]);   // invalid pts never read
    } else {
        int j = vbid - p.blocksA;
        int per_b = p.pbB * p.CB;
        b  = j / per_b;
        int r = j - b * per_b;
        c  = r / p.pbB;
        pb = r - c * p.pbB;
        pts = p.hand_verts; tverts = p.obj_verts; tfaces = p.obj_faces;
        slots = p.hitsB;
        P = p.Nh; T = p.Fo; Nv = p.No; chunk = p.chunkB;
        tlim = min(p.Fo, p.ofsplit[b]); plim = p.Nh;
    }

    int tStart = c * chunk;
    if (tStart >= tlim) return;               // block-uniform
    if (pb * PTS_PER_BLK >= plim) return;     // block-uniform
    int nTri = min(tStart + chunk, tlim) - tStart;

    if (tid < nTri) {
        int t = tStart + tid;
        tri_pre_one(tverts + (size_t)b * Nv * 3,
                    tfaces + ((size_t)b * T + t) * 3,
                    s_tri + (size_t)tid * 4);
    }

    int p1 = pb * PTS_PER_BLK + tid;
    int p2 = p1 + 256;
    bool act1 = p1 < plim, act2 = p2 < plim;
    float q1x = 0.f, q1y = 0.f, q1z = 0.f;
    float q2x = 0.f, q2y = 0.f, q2z = 0.f;
    if (act1) {
        const float* q = pts + ((size_t)b * P + p1) * 3;
        q1x = q[0]; q1y = q[1]; q1z = q[2];
    }
    if (act2) {
        const float* q = pts + ((size_t)b * P + p2) * 3;
        q2x = q[0]; q2y = q[1]; q2z = q[2];
    }
    __syncthreads();

    if (!act1) return;                        // act1 false => act2 false
    int cnt1 = 0, cnt2 = 0;
    if (__any(act2)) {
        for (int i = 0; i < nTri; ++i) {
            const float4 f0 = s_tri[(i<<2)+0];
            const float4 f1 = s_tri[(i<<2)+1];
            const float4 f2 = s_tri[(i<<2)+2];
            const float4 f3 = s_tri[(i<<2)+3];
            cnt1 += mt_test(q1x, q1y, q1z, f0, f1, f2, f3);
            cnt2 += mt_test(q2x, q2y, q2z, f0, f1, f2, f3);
        }
    } else {
        for (int i = 0; i < nTri; ++i) {
            const float4 f0 = s_tri[(i<<2)+0];
            const float4 f1 = s_tri[(i<<2)+1];
            const float4 f2 = s_tri[(i<<2)+2];
            const float4 f3 = s_tri[(i<<2)+3];
            cnt1 += mt_test(q1x, q1y, q1z, f0, f1, f2, f3);
        }
    }
    int* base = slots + (size_t)b * P;
    if (cnt1)         atomicAdd(&base[p1], cnt1);   // integer sum — exact
    if (act2 && cnt2) atomicAdd(&base[p2], cnt2);
}

// ---------------------------------------------------------------------------
// One argmin wave. Packed (dist<<32)|idx min => np.argmin tie-break.
// ---------------------------------------------------------------------------
__device__ __forceinline__ void min_one(const Params& p, int w, int lane) {
#pragma clang fp contract(off)
    int nHand = p.B * p.Nh;
    const float* refv; const float* loopv; int loopN; float* outp;
    if (w < nHand) {
        int b = w / p.Nh;
        int n = w - b * p.Nh;
        refv  = p.hand_verts + ((size_t)b * p.Nh + n) * 3;
        loopv = p.obj_verts + (size_t)b * p.No * 3;
        loopN = p.ovsplit[b];
        outp  = p.anchor_h + (size_t)b * p.Nh + n;
    } else {
        int j = w - nHand;
        int b = j / p.No;
        int m = j - b * p.No;
        if (m >= p.ovsplit[b]) return;
        refv  = p.obj_verts + ((size_t)b * p.No + m) * 3;
        loopv = p.hand_verts + (size_t)b * p.Nh * 3;
        loopN = p.Nh;
        outp  = p.anchor_o + (size_t)b * p.No + m;
    }
    float hx = refv[0], hy = refv[1], hz = refv[2];
    float rx = (hx*hx + hy*hy) + hz*hz;
    unsigned long long best = ~0ull;
    for (int m = lane; m < loopN; m += 64) {
        float ox = loopv[m*3+0], oy = loopv[m*3+1], oz = loopv[m*3+2];
        float ry = (ox*ox + oy*oy) + oz*oz;
        float zz = (hx*ox + hy*oy) + hz*oz;
        float d = (rx + ry) - 2.0f * zz;
        unsigned long long e = ((unsigned long long)__float_as_uint(d) << 32) | (unsigned)m;
        if (e < best) best = e;
    }
    for (int off = 32; off > 0; off >>= 1) {
        unsigned long long o = __shfl_xor(best, off, 64);
        if (o < best) best = o;
    }
    if (lane == 0) {
        int idx = (best == ~0ull) ? 0 : (int)(best & 0xffffffffu);
        const float* cv = loopv + (size_t)idx * 3;
        float dx = cv[0] - hx, dy = cv[1] - hy, dz = cv[2] - hz;
        *outp = sqrtf((dx*dx + dy*dy) + dz*dz);
    }
}

// ---------------------------------------------------------------------------
// mega: [raycast VBs | argmin blocks] — no tail sync; resets done counter.
// ---------------------------------------------------------------------------
__global__ __launch_bounds__(256) void mega(Params p) {
    __shared__ float4 s_tri[MAXCHUNK_F4];
    const int tid = threadIdx.x;
    const int bid = blockIdx.x;
    if (bid == 0 && tid == 0) *p.done = 0u;   // visible to reduce_fin at boundary
    const int nRay = p.blocksA + p.blocksB;
    if (bid < nRay) {
        raycast_vb(p, bid, tid, s_tri);
    } else {
        int w = (bid - nRay) * 4 + (tid >> 6);
        if (w < p.B * (p.Nh + p.No)) min_one(p, w, tid & 63);
    }
}

// ---------------------------------------------------------------------------
// reduce_fin: 128 single-wave blocks (R8 tree verbatim; parity is now a
// single int load per point). Done-counter + fence finalize.
// ---------------------------------------------------------------------------
__global__ __launch_bounds__(64) void reduce_fin(Params p) {
    const int r    = blockIdx.x;
    const int b    = r >> 4;
    const int wv   = r & 15;
    const int lane = threadIdx.x;
    const int vt   = wv * 64 + lane;          // virtual tid 0..1023
    float s0=0.f,s1=0.f,s2=0.f,s3=0.f,s4=0.f,s5=0.f;

    for (int n = vt; n < p.Nh; n += 1024) {
        int par = p.hitsB[(size_t)b * p.Nh + n];
        bool ext = (par & 1) == 0;
        float val = 25.0f * tanhf(p.anchor_h[(size_t)b*p.Nh + n] / 25.0f);
        if (ext) { s0 += val; s1 += 1.0f; } else { s2 += val; s3 += 1.0f; }
    }
    int split = p.ovsplit[b];
    for (int m = vt; m < split; m += 1024) {
        int par = p.hitsA[(size_t)b * p.No + m];
        if (par & 1) {                                   // interior & valid
            s4 += 25.0f * tanhf(p.anchor_o[(size_t)b*p.No + m] / 25.0f);
            s5 += 1.0f;
        }
    }
    for (int off = 32; off > 0; off >>= 1) {
        s0 += __shfl_xor(s0, off, 64);
        s1 += __shfl_xor(s1, off, 64);
        s2 += __shfl_xor(s2, off, 64);
        s3 += __shfl_xor(s3, off, 64);
        s4 += __shfl_xor(s4, off, 64);
        s5 += __shfl_xor(s5, off, 64);
    }

    __shared__ bool s_last;
    if (lane == 0) {
        float* q = p.partials + ((size_t)(b * 16 + wv)) * 6;
        q[0]=s0; q[1]=s1; q[2]=s2; q[3]=s3; q[4]=s4; q[5]=s5;
        __threadfence();                     // release partials
        unsigned int old = atomicAdd(p.done, 1u);
        s_last = (old == (unsigned int)(gridDim.x - 1));
    }
    __syncthreads();
    if (!s_last) return;
    __threadfence();                         // acquire others' partials

    __shared__ float s_red[16][6];
    if (lane < p.B && lane < 16) {
        int bb = lane;
        float t0=0.f,t1=0.f,t2=0.f,t3=0.f,t4=0.f,t5=0.f;
        for (int w2 = 0; w2 < 16; ++w2) {     // same wave order as old loop
            const float* q = p.partials + ((size_t)(bb * 16 + w2)) * 6;
            t0 += q[0]; t1 += q[1]; t2 += q[2];
            t3 += q[3]; t4 += q[4]; t5 += q[5];
        }
        p.out[2 + bb]  = (t1 > 0.f) ? t0 / fmaxf(t1, 1.f) : 0.f;
        float ph       = (t3 > 0.f) ? t2 / fmaxf(t3, 1.f) : 0.f;
        float po       = (t5 > 0.f) ? t4 / fmaxf(t5, 1.f) : 0.f;
        p.out[10 + bb] = ph + po;
        s_red[bb][0]=t0; s_red[bb][1]=t1; s_red[bb][2]=t2;
        s_red[bb][3]=t3; s_red[bb][4]=t4; s_red[bb][5]=t5;
    }
    __syncthreads();
    if (lane == 0) {
        float sm=0.f,cm=0.f,sph=0.f,cph=0.f,spo=0.f,cpo=0.f;
        for (int bb = 0; bb < p.B; ++bb) {    // same batch order as old final
            sm  += s_red[bb][0]; cm  += s_red[bb][1]; sph += s_red[bb][2];
            cph += s_red[bb][3]; spo += s_red[bb][4]; cpo += s_red[bb][5];
        }
        float missed = (cm  > 0.f) ? sm  / fmaxf(cm , 1.f) : 0.f;
        float ph     = (cph > 0.f) ? sph / fmaxf(cph, 1.f) : 0.f;
        float po     = (cpo > 0.f) ? spo / fmaxf(cpo, 1.f) : 0.f;
        p.out[0] = missed;
        p.out[1] = ph + po;
    }
}

// ---------------------------------------------------------------------------
extern "C" void kernel_launch(void* const* d_in, const int* in_sizes, int n_in,
                              void* d_out, int out_size, void* d_ws, size_t ws_size,
                              hipStream_t stream) {
    Params p;
    p.hand_verts = (const float*)d_in[0];
    p.hand_faces = (const int*)d_in[1];
    p.obj_verts  = (const float*)d_in[2];
    p.obj_faces  = (const int*)d_in[3];
    p.ovsplit    = (const int*)d_in[4];
    p.ofsplit    = (const int*)d_in[5];
    p.out        = (float*)d_out;

    p.B  = in_sizes[4];
    p.Nh = in_sizes[0] / (3 * p.B);
    p.Fh = in_sizes[1] / (3 * p.B);
    p.No = in_sizes[2] / (3 * p.B);
    p.Fo = in_sizes[3] / (3 * p.B);

    p.CA = 32; p.CB = 64;
    p.chunkA = (p.Fh + p.CA - 1) / p.CA;       // 49 for Fh=1538 (196 f4 <= 256)
    p.chunkB = (p.Fo + p.CB - 1) / p.CB;       // 63 for Fo=4000 (252 f4 <= 256)
    p.pbA = (p.No + PTS_PER_BLK - 1) / PTS_PER_BLK;   // 4
    p.pbB = (p.Nh + PTS_PER_BLK - 1) / PTS_PER_BLK;   // 2
    p.blocksA = p.pbA * p.CA * p.B;            // 1024
    p.blocksB = p.pbB * p.CB * p.B;            // 1024

    char* ws = (char*)d_ws;
    size_t off = 0;
    auto alloc = [&](size_t bytes) -> void* {
        void* q = ws + off;
        off = (off + bytes + 255) & ~(size_t)255;
        return q;
    };
    size_t hitsOff = off;
    p.hitsA    = (int*)   alloc((size_t)p.B * p.No * sizeof(int));
    p.hitsB    = (int*)   alloc((size_t)p.B * p.Nh * sizeof(int));
    size_t hitsBytes = off - hitsOff;          // contiguous span, one memset
    p.anchor_h = (float*) alloc((size_t)p.B * p.Nh * sizeof(float));
    p.anchor_o = (float*) alloc((size_t)p.B * p.No * sizeof(float));
    p.partials = (float*) alloc((size_t)p.B * 16 * 6 * sizeof(float));
    p.done     = (unsigned int*)alloc(sizeof(unsigned int));

    int totalMin   = p.B * (p.Nh + p.No);
    int nMinBlocks = (totalMin + 3) / 4;       // 4 argmin waves per block
    int grid = p.blocksA + p.blocksB + nMinBlocks;

    hipMemsetAsync((void*)p.hitsA, 0, hitsBytes, stream);
    mega<<<grid, 256, 0, stream>>>(p);
    reduce_fin<<<p.B * 16, 64, 0, stream>>>(p);
}